// Round 4
// baseline (277.326 us; speedup 1.0000x reference)
//
#include <hip/hip_runtime.h>

// TrilinearInterpolation: 33^3 x 3ch LUT applied to 8x3x1024x1024 image.
// d_in[0] = lut_count (int32, unused), d_in[1] = lut (f32, 3*35937),
// d_in[2] = x (f32, 8*3*1024*1024).
// d_out   = [lut copy (107811 f32)] ++ [output (25165824 f32)].
//
// Cell-table strategy: rebuild LUT into d_ws so each of 32^3 cells holds its
// 8 corners x 3 channels contiguously (24 floats = 96 B, 32B-aligned -> every
// pixel's gather touches exactly 2 cache lines instead of ~12).
//
// Within-probe A/B: images 0-3 via 1-pixel/thread (TLP), images 4-7 via
// 4-pixel/thread dwordx4 (ILP). rocprof per-dispatch timing decides winner.
//
// NOTE: __builtin_nontemporal_* requires native vector types, not HIP's
// float4 struct -> use ext_vector_type(4).

typedef float f32x4 __attribute__((ext_vector_type(4)));

#define DIM    33
#define D2     (DIM * DIM)          // 1089
#define SHIFT  (DIM * DIM * DIM)    // 35937
#define LUT_ELEMS (3 * SHIFT)       // 107811
#define NCELL  32768                // 32^3
#define RECF   24                   // floats per cell record
#define PLANE  1048576              // 1024*1024
#define NPIX   (8 * PLANE)          // 8388608 pixels

// ---- build cell table: one thread per output float (coalesced writes) ----
__global__ __launch_bounds__(256) void build_cells_kernel(
    const float* __restrict__ lut, float* __restrict__ cells) {
    int t = blockIdx.x * 256 + threadIdx.x;
    if (t >= NCELL * RECF) return;
    int cell   = t / RECF;
    int j      = t - cell * RECF;     // j = corner*3 + ch
    int corner = j / 3;
    int ch     = j - corner * 3;
    int ri = cell & 31, gi = (cell >> 5) & 31, bi = cell >> 10;
    int dr = corner & 1, dg = (corner >> 1) & 1, db = corner >> 2;
    cells[t] = lut[ch * SHIFT + (bi + db) * D2 + (gi + dg) * DIM + (ri + dr)];
}

// ---- per-pixel interpolation from the cell table ----
__device__ __forceinline__ void lut_one(const float* __restrict__ cells,
                                        float r, float g, float b,
                                        float& outr, float& outg, float& outb) {
    const float BIN = (float)(1.000001 / 32.0);   // matches f32(1.000001/32)
    float rs = r / BIN, gs = g / BIN, bs = b / BIN;
    float rf = floorf(rs), gf = floorf(gs), bf = floorf(bs);
    float rd = rs - rf, gd = gs - gf, bd = bs - bf;
    int ri = (int)rf, gi = (int)gf, bi = (int)bf;
    int cell = (bi << 10) | (gi << 5) | ri;

    const f32x4* rec = (const f32x4*)(cells + cell * 24);
    f32x4 q0 = rec[0], q1 = rec[1], q2 = rec[2];
    f32x4 q3 = rec[3], q4 = rec[4], q5 = rec[5];
    float v[24];
    *(f32x4*)(v +  0) = q0;
    *(f32x4*)(v +  4) = q1;
    *(f32x4*)(v +  8) = q2;
    *(f32x4*)(v + 12) = q3;
    *(f32x4*)(v + 16) = q4;
    *(f32x4*)(v + 20) = q5;

    float omr = 1.0f - rd, omg = 1.0f - gd, omb = 1.0f - bd;
    float w000 = omr * omg * omb;
    float w100 = rd  * omg * omb;
    float w010 = omr * gd  * omb;
    float w110 = rd  * gd  * omb;
    float w001 = omr * omg * bd;
    float w101 = rd  * omg * bd;
    float w011 = omr * gd  * bd;
    float w111 = rd  * gd  * bd;

    // corner order: bit0=dr, bit1=dg, bit2=db; 3 channels each.
    // Sum order matches reference (000,100,010,110,001,101,011,111).
    outr = w000*v[0] + w100*v[3] + w010*v[6]  + w110*v[9]  + w001*v[12] + w101*v[15] + w011*v[18] + w111*v[21];
    outg = w000*v[1] + w100*v[4] + w010*v[7]  + w110*v[10] + w001*v[13] + w101*v[16] + w011*v[19] + w111*v[22];
    outb = w000*v[2] + w100*v[5] + w010*v[8]  + w110*v[11] + w001*v[14] + w101*v[17] + w011*v[20] + w111*v[23];
}

// ---- Variant A: 1 pixel/thread, max occupancy (TLP) ----
__global__ __launch_bounds__(256) void apply_A_kernel(
    const float* __restrict__ x, const float* __restrict__ cells,
    float* __restrict__ out) {
    int t = blockIdx.x * 256 + threadIdx.x;   // one pixel per thread
    int b = t >> 20;                          // image index within this range
    int p = t & (PLANE - 1);
    const float* xb = x + (size_t)b * (3 * PLANE) + p;
    float r  = __builtin_nontemporal_load(xb);
    float g  = __builtin_nontemporal_load(xb + PLANE);
    float bl = __builtin_nontemporal_load(xb + 2 * PLANE);
    float orr, og, obl;
    lut_one(cells, r, g, bl, orr, og, obl);
    float* ob = out + (size_t)b * (3 * PLANE) + p;
    __builtin_nontemporal_store(orr, ob);
    __builtin_nontemporal_store(og,  ob + PLANE);
    __builtin_nontemporal_store(obl, ob + 2 * PLANE);
}

// ---- Variant B: 4 pixels/thread, dwordx4 streaming (ILP) ----
__global__ __launch_bounds__(256) void apply_B_kernel(
    const float* __restrict__ x, const float* __restrict__ cells,
    float* __restrict__ out) {
    int t = blockIdx.x * 256 + threadIdx.x;   // 4 pixels per thread
    int b = t >> 18;                          // PLANE/4 = 2^18 threads/image
    int p = (t & ((PLANE / 4) - 1)) << 2;
    const float* xb = x + (size_t)b * (3 * PLANE) + p;
    f32x4 r4 = __builtin_nontemporal_load((const f32x4*)(xb));
    f32x4 g4 = __builtin_nontemporal_load((const f32x4*)(xb + PLANE));
    f32x4 b4 = __builtin_nontemporal_load((const f32x4*)(xb + 2 * PLANE));

    f32x4 o0, o1, o2;
    #pragma unroll
    for (int i = 0; i < 4; ++i) {
        float orr, og, ob;
        lut_one(cells, r4[i], g4[i], b4[i], orr, og, ob);
        o0[i] = orr; o1[i] = og; o2[i] = ob;
    }

    float* o = out + (size_t)b * (3 * PLANE) + p;
    __builtin_nontemporal_store(o0, (f32x4*)(o));
    __builtin_nontemporal_store(o1, (f32x4*)(o + PLANE));
    __builtin_nontemporal_store(o2, (f32x4*)(o + 2 * PLANE));
}

// ---- fallback: gather straight from the (3,35937) layout (if ws too small) ----
__global__ __launch_bounds__(256) void apply_direct_kernel(
    const float* __restrict__ x, const float* __restrict__ lut,
    float* __restrict__ out) {
    int t = blockIdx.x * 256 + threadIdx.x;
    int b = t >> 20;
    int p = t & (PLANE - 1);
    const float* xb = x + (size_t)b * (3 * PLANE) + p;
    float r  = xb[0];
    float g  = xb[PLANE];
    float bl = xb[2 * PLANE];

    const float BIN = (float)(1.000001 / 32.0);
    float rs = r / BIN, gs = g / BIN, bs = bl / BIN;
    float rf = floorf(rs), gf = floorf(gs), bf = floorf(bs);
    float rd = rs - rf, gd = gs - gf, bd = bs - bf;
    int ri = (int)rf, gi = (int)gf, bi = (int)bf;
    int id000 = ri + gi * DIM + bi * D2;

    float omr = 1.0f - rd, omg = 1.0f - gd, omb = 1.0f - bd;
    float w000 = omr*omg*omb, w100 = rd*omg*omb, w010 = omr*gd*omb, w110 = rd*gd*omb;
    float w001 = omr*omg*bd,  w101 = rd*omg*bd,  w011 = omr*gd*bd,  w111 = rd*gd*bd;

    float* ob = out + (size_t)b * (3 * PLANE) + p;
    #pragma unroll
    for (int ch = 0; ch < 3; ++ch) {
        const float* L = lut + ch * SHIFT + id000;
        float acc = w000 * L[0]        + w100 * L[1]
                  + w010 * L[DIM]      + w110 * L[DIM + 1]
                  + w001 * L[D2]       + w101 * L[D2 + 1]
                  + w011 * L[D2 + DIM] + w111 * L[D2 + DIM + 1];
        ob[(size_t)ch * PLANE] = acc;
    }
}

extern "C" void kernel_launch(void* const* d_in, const int* in_sizes, int n_in,
                              void* d_out, int out_size, void* d_ws, size_t ws_size,
                              hipStream_t stream) {
    const float* lut = (const float*)d_in[1];
    const float* x   = (const float*)d_in[2];
    float* out = (float*)d_out;

    // Output tuple element 0: the lut, passed through.
    (void)hipMemcpyAsync(out, lut, (size_t)LUT_ELEMS * sizeof(float),
                         hipMemcpyDeviceToDevice, stream);

    float* outimg = out + LUT_ELEMS;
    const size_t cells_bytes = (size_t)NCELL * RECF * sizeof(float); // 3 MiB

    if (ws_size >= cells_bytes) {
        float* cells = (float*)d_ws;
        build_cells_kernel<<<(NCELL * RECF + 255) / 256, 256, 0, stream>>>(lut, cells);

        // A/B split: images 0-3 via variant A, images 4-7 via variant B.
        const int half_pix = NPIX / 2;                      // 4 images
        apply_A_kernel<<<half_pix / 256, 256, 0, stream>>>(x, cells, outimg);

        const size_t off = (size_t)4 * (3 * PLANE);         // start of image 4
        apply_B_kernel<<<(half_pix / 4) / 256, 256, 0, stream>>>(
            x + off, cells, outimg + off);
    } else {
        apply_direct_kernel<<<NPIX / 256, 256, 0, stream>>>(x, lut, outimg);
    }
}

// Round 5
// 246.069 us; speedup vs baseline: 1.1270x; 1.1270x over previous
//
#include <hip/hip_runtime.h>

// TrilinearInterpolation: 33^3 x 3ch LUT applied to 8x3x1024x1024 image.
// d_in[0] = lut_count (unused), d_in[1] = lut (f32 3*35937), d_in[2] = x.
// d_out = [lut copy (107811)] ++ [output (25165824)].
//
// R4 finding: apply phase is scattered-request-bound (~2 cyc per L1-missing
// line request; 6 req/pixel). Fix: 128B-padded cell records + 4-lane
// cooperative gather (2 coalesced line-req/pixel) + LDS exchange with XOR-16
// swizzle (bank-balanced).

typedef float f32x4 __attribute__((ext_vector_type(4)));

#define DIM    33
#define D2     (DIM * DIM)
#define SHIFT  (DIM * DIM * DIM)
#define LUT_ELEMS (3 * SHIFT)
#define NCELL  32768
#define PLANE  1048576
#define NPIX   (8 * PLANE)

// ---------- build 128B-padded records: cell -> 8 corners x 3ch (+8 pad) ----------
__global__ __launch_bounds__(256) void build_cells128_kernel(
    const float* __restrict__ lut, float* __restrict__ cells) {
    int t = blockIdx.x * 256 + threadIdx.x;     // NCELL*32 threads
    int cell = t >> 5;
    int j = t & 31;                             // j = corner*3 + ch for j<24
    float v = 0.0f;
    if (j < 24) {
        int corner = j / 3;
        int ch = j - corner * 3;
        int ri = cell & 31, gi = (cell >> 5) & 31, bi = cell >> 10;
        int dr = corner & 1, dg = (corner >> 1) & 1, db = corner >> 2;
        v = lut[ch * SHIFT + (bi + db) * D2 + (gi + dg) * DIM + (ri + dr)];
    }
    cells[t] = v;
}

// ---------- cooperative apply: 1 px/thread, 4-lane group gather ----------
__global__ __launch_bounds__(256) void apply_coop_kernel(
    const float* __restrict__ x, const float* __restrict__ cells,
    float* __restrict__ out) {
    __shared__ float recs[256 * 32];   // 32 KB: 256 slots x 128 B
    __shared__ int cellIdx[256];

    const int tid = threadIdx.x;
    const int t = blockIdx.x * 256 + tid;
    const int b = t >> 20;
    const int p = t & (PLANE - 1);
    const float* xb = x + (size_t)b * (3 * PLANE) + p;
    float r  = __builtin_nontemporal_load(xb);
    float g  = __builtin_nontemporal_load(xb + PLANE);
    float bl = __builtin_nontemporal_load(xb + 2 * PLANE);

    const float BIN = (float)(1.000001 / 32.0);
    float rs = r / BIN, gs = g / BIN, bs = bl / BIN;
    float rf = floorf(rs), gf = floorf(gs), bf = floorf(bs);
    float rd = rs - rf, gd = gs - gf, bd = bs - bf;
    int cell = (((int)bf) << 10) | (((int)gf) << 5) | ((int)rf);
    cellIdx[tid] = cell;
    __syncthreads();

    // Gather: per wave, 16 groups of 4 lanes; group fetches one pixel's
    // 128B record in 2 instructions (1 line-request each after coalescing).
    const int lane = tid & 63;
    const int wavebase = tid & 192;            // wave * 64
    #pragma unroll
    for (int r4 = 0; r4 < 4; ++r4) {
        int pl = wavebase + r4 * 16 + (lane >> 2);   // slot this group serves
        int c  = cellIdx[pl];
        int k  = pl & 7;                              // XOR swizzle key
        const f32x4* src = (const f32x4*)(cells + (size_t)c * 32);
        int cl0 = lane & 3;                           // logical chunks 0..3
        int cl1 = 4 + (lane & 3);                     // 4..7 (6,7 = pad)
        f32x4 v0 = src[cl0];
        f32x4 v1 = src[cl1];
        f32x4* row = (f32x4*)(recs + pl * 32);
        row[cl0 ^ k] = v0;
        row[cl1 ^ k] = v1;
    }
    __syncthreads();

    // Read back own record (XOR-16 swizzle -> bank-balanced b128 reads).
    int k = tid & 7;
    const f32x4* row = (const f32x4*)(recs + tid * 32);
    float v[24];
    #pragma unroll
    for (int c = 0; c < 6; ++c)
        *(f32x4*)(v + 4 * c) = row[c ^ k];

    float omr = 1.0f - rd, omg = 1.0f - gd, omb = 1.0f - bd;
    float w000 = omr * omg * omb;
    float w100 = rd  * omg * omb;
    float w010 = omr * gd  * omb;
    float w110 = rd  * gd  * omb;
    float w001 = omr * omg * bd;
    float w101 = rd  * omg * bd;
    float w011 = omr * gd  * bd;
    float w111 = rd  * gd  * bd;

    float orr = w000*v[0] + w100*v[3] + w010*v[6]  + w110*v[9]  + w001*v[12] + w101*v[15] + w011*v[18] + w111*v[21];
    float og  = w000*v[1] + w100*v[4] + w010*v[7]  + w110*v[10] + w001*v[13] + w101*v[16] + w011*v[19] + w111*v[22];
    float obl = w000*v[2] + w100*v[5] + w010*v[8]  + w110*v[11] + w001*v[14] + w101*v[17] + w011*v[20] + w111*v[23];

    float* ob = out + (size_t)b * (3 * PLANE) + p;
    __builtin_nontemporal_store(orr, ob);
    __builtin_nontemporal_store(og,  ob + PLANE);
    __builtin_nontemporal_store(obl, ob + 2 * PLANE);
}

// ---------- fallback tier 1: 96B records, 1 px/thread (R4's apply_A) ----------
__global__ __launch_bounds__(256) void build_cells96_kernel(
    const float* __restrict__ lut, float* __restrict__ cells) {
    int t = blockIdx.x * 256 + threadIdx.x;
    if (t >= NCELL * 24) return;
    int cell = t / 24;
    int j = t - cell * 24;
    int corner = j / 3;
    int ch = j - corner * 3;
    int ri = cell & 31, gi = (cell >> 5) & 31, bi = cell >> 10;
    int dr = corner & 1, dg = (corner >> 1) & 1, db = corner >> 2;
    cells[t] = lut[ch * SHIFT + (bi + db) * D2 + (gi + dg) * DIM + (ri + dr)];
}

__global__ __launch_bounds__(256) void apply_A_kernel(
    const float* __restrict__ x, const float* __restrict__ cells,
    float* __restrict__ out) {
    int t = blockIdx.x * 256 + threadIdx.x;
    int b = t >> 20;
    int p = t & (PLANE - 1);
    const float* xb = x + (size_t)b * (3 * PLANE) + p;
    float r  = __builtin_nontemporal_load(xb);
    float g  = __builtin_nontemporal_load(xb + PLANE);
    float bl = __builtin_nontemporal_load(xb + 2 * PLANE);

    const float BIN = (float)(1.000001 / 32.0);
    float rs = r / BIN, gs = g / BIN, bs = bl / BIN;
    float rf = floorf(rs), gf = floorf(gs), bf = floorf(bs);
    float rd = rs - rf, gd = gs - gf, bd = bs - bf;
    int cell = (((int)bf) << 10) | (((int)gf) << 5) | ((int)rf);

    const f32x4* rec = (const f32x4*)(cells + cell * 24);
    float v[24];
    *(f32x4*)(v +  0) = rec[0];
    *(f32x4*)(v +  4) = rec[1];
    *(f32x4*)(v +  8) = rec[2];
    *(f32x4*)(v + 12) = rec[3];
    *(f32x4*)(v + 16) = rec[4];
    *(f32x4*)(v + 20) = rec[5];

    float omr = 1.0f - rd, omg = 1.0f - gd, omb = 1.0f - bd;
    float w000 = omr*omg*omb, w100 = rd*omg*omb, w010 = omr*gd*omb, w110 = rd*gd*omb;
    float w001 = omr*omg*bd,  w101 = rd*omg*bd,  w011 = omr*gd*bd,  w111 = rd*gd*bd;

    float orr = w000*v[0] + w100*v[3] + w010*v[6]  + w110*v[9]  + w001*v[12] + w101*v[15] + w011*v[18] + w111*v[21];
    float og  = w000*v[1] + w100*v[4] + w010*v[7]  + w110*v[10] + w001*v[13] + w101*v[16] + w011*v[19] + w111*v[22];
    float obl = w000*v[2] + w100*v[5] + w010*v[8]  + w110*v[11] + w001*v[14] + w101*v[17] + w011*v[20] + w111*v[23];

    float* ob = out + (size_t)b * (3 * PLANE) + p;
    __builtin_nontemporal_store(orr, ob);
    __builtin_nontemporal_store(og,  ob + PLANE);
    __builtin_nontemporal_store(obl, ob + 2 * PLANE);
}

// ---------- fallback tier 2: direct gather from original layout ----------
__global__ __launch_bounds__(256) void apply_direct_kernel(
    const float* __restrict__ x, const float* __restrict__ lut,
    float* __restrict__ out) {
    int t = blockIdx.x * 256 + threadIdx.x;
    int b = t >> 20;
    int p = t & (PLANE - 1);
    const float* xb = x + (size_t)b * (3 * PLANE) + p;
    float r  = xb[0];
    float g  = xb[PLANE];
    float bl = xb[2 * PLANE];

    const float BIN = (float)(1.000001 / 32.0);
    float rs = r / BIN, gs = g / BIN, bs = bl / BIN;
    float rf = floorf(rs), gf = floorf(gs), bf = floorf(bs);
    float rd = rs - rf, gd = gs - gf, bd = bs - bf;
    int id000 = (int)rf + (int)gf * DIM + (int)bf * D2;

    float omr = 1.0f - rd, omg = 1.0f - gd, omb = 1.0f - bd;
    float w000 = omr*omg*omb, w100 = rd*omg*omb, w010 = omr*gd*omb, w110 = rd*gd*omb;
    float w001 = omr*omg*bd,  w101 = rd*omg*bd,  w011 = omr*gd*bd,  w111 = rd*gd*bd;

    float* ob = out + (size_t)b * (3 * PLANE) + p;
    #pragma unroll
    for (int ch = 0; ch < 3; ++ch) {
        const float* L = lut + ch * SHIFT + id000;
        float acc = w000 * L[0]        + w100 * L[1]
                  + w010 * L[DIM]      + w110 * L[DIM + 1]
                  + w001 * L[D2]       + w101 * L[D2 + 1]
                  + w011 * L[D2 + DIM] + w111 * L[D2 + DIM + 1];
        ob[(size_t)ch * PLANE] = acc;
    }
}

extern "C" void kernel_launch(void* const* d_in, const int* in_sizes, int n_in,
                              void* d_out, int out_size, void* d_ws, size_t ws_size,
                              hipStream_t stream) {
    const float* lut = (const float*)d_in[1];
    const float* x   = (const float*)d_in[2];
    float* out = (float*)d_out;

    (void)hipMemcpyAsync(out, lut, (size_t)LUT_ELEMS * sizeof(float),
                         hipMemcpyDeviceToDevice, stream);

    float* outimg = out + LUT_ELEMS;
    const size_t bytes128 = (size_t)NCELL * 32 * sizeof(float);  // 4 MiB
    const size_t bytes96  = (size_t)NCELL * 24 * sizeof(float);  // 3 MiB

    if (ws_size >= bytes128) {
        float* cells = (float*)d_ws;
        build_cells128_kernel<<<NCELL * 32 / 256, 256, 0, stream>>>(lut, cells);
        apply_coop_kernel<<<NPIX / 256, 256, 0, stream>>>(x, cells, outimg);
    } else if (ws_size >= bytes96) {
        float* cells = (float*)d_ws;
        build_cells96_kernel<<<(NCELL * 24 + 255) / 256, 256, 0, stream>>>(lut, cells);
        apply_A_kernel<<<NPIX / 256, 256, 0, stream>>>(x, cells, outimg);
    } else {
        apply_direct_kernel<<<NPIX / 256, 256, 0, stream>>>(x, lut, outimg);
    }
}

// Round 10
// 241.942 us; speedup vs baseline: 1.1463x; 1.0171x over previous
//
#include <hip/hip_runtime.h>

// TrilinearInterpolation: 33^3 x 3ch LUT applied to 8x3x1024x1024 image.
// d_out = [lut copy (107811)] ++ [output (25165824)].
//
// R5 post-mortem: 4-lane coop gather worked but (a) LDS write phase had a
// 2x bank-phase conflict (11.5M conflict cycles): with 8-lane-per-phase b128
// processing, chunk ids must cover 0..7 within every 8 consecutive lanes.
// (b) 33KB LDS capped occupancy at ~12 waves/CU.
// This round: C = phase-balanced chunk mapping (images 0-3);
//             D = C + 16KB double-pumped exchange for 2x occupancy (4-7).

typedef float f32x4 __attribute__((ext_vector_type(4)));

#define DIM    33
#define D2     (DIM * DIM)
#define SHIFT  (DIM * DIM * DIM)
#define LUT_ELEMS (3 * SHIFT)
#define NCELL  32768
#define PLANE  1048576
#define NPIX   (8 * PLANE)

// ---------- build 128B-padded records: cell -> 8 corners x 3ch (+8 pad) ----------
__global__ __launch_bounds__(256) void build_cells128_kernel(
    const float* __restrict__ lut, float* __restrict__ cells) {
    int t = blockIdx.x * 256 + threadIdx.x;     // NCELL*32 threads
    int cell = t >> 5;
    int j = t & 31;
    float v = 0.0f;
    if (j < 24) {
        int corner = j / 3;
        int ch = j - corner * 3;
        int ri = cell & 31, gi = (cell >> 5) & 31, bi = cell >> 10;
        int dr = corner & 1, dg = (corner >> 1) & 1, db = corner >> 2;
        v = lut[ch * SHIFT + (bi + db) * D2 + (gi + dg) * DIM + (ri + dr)];
    }
    cells[t] = v;
}

// ---------- shared helpers ----------
__device__ __forceinline__ void decode_px(float r, float g, float bl,
                                          int& cell, float& rd, float& gd, float& bd) {
    const float BIN = (float)(1.000001 / 32.0);
    float rs = r / BIN, gs = g / BIN, bs = bl / BIN;
    float rf = floorf(rs), gf = floorf(gs), bf = floorf(bs);
    rd = rs - rf; gd = gs - gf; bd = bs - bf;
    cell = (((int)bf) << 10) | (((int)gf) << 5) | ((int)rf);
}

__device__ __forceinline__ void tri_out(const float* v, float rd, float gd, float bd,
                                        float& o0, float& o1, float& o2) {
    float omr = 1.0f - rd, omg = 1.0f - gd, omb = 1.0f - bd;
    float w000 = omr*omg*omb, w100 = rd*omg*omb, w010 = omr*gd*omb, w110 = rd*gd*omb;
    float w001 = omr*omg*bd,  w101 = rd*omg*bd,  w011 = omr*gd*bd,  w111 = rd*gd*bd;
    o0 = w000*v[0] + w100*v[3] + w010*v[6]  + w110*v[9]  + w001*v[12] + w101*v[15] + w011*v[18] + w111*v[21];
    o1 = w000*v[1] + w100*v[4] + w010*v[7]  + w110*v[10] + w001*v[13] + w101*v[16] + w011*v[19] + w111*v[22];
    o2 = w000*v[2] + w100*v[5] + w010*v[8]  + w110*v[11] + w001*v[14] + w101*v[17] + w011*v[20] + w111*v[23];
}

// ---------- Variant C: phase-balanced swizzle, full 256-row exchange ----------
__global__ __launch_bounds__(256) void apply_coopC_kernel(
    const float* __restrict__ x, const float* __restrict__ cells,
    float* __restrict__ out) {
    __shared__ float recs[256 * 32];   // 32 KB
    __shared__ int cellIdx[256];

    const int tid = threadIdx.x;
    const int t = blockIdx.x * 256 + tid;
    const int b = t >> 20;
    const int p = t & (PLANE - 1);
    const float* xb = x + (size_t)b * (3 * PLANE) + p;
    float r  = __builtin_nontemporal_load(xb);
    float g  = __builtin_nontemporal_load(xb + PLANE);
    float bl = __builtin_nontemporal_load(xb + 2 * PLANE);
    int cell; float rd, gd, bd;
    decode_px(r, g, bl, cell, rd, gd, bd);
    cellIdx[tid] = cell;
    __syncthreads();

    const int lane = tid & 63;
    const int wavebase = tid & 192;
    const int grp = lane >> 2;
    // logical chunks: 8-lane phase must cover chunk ids 0..7 after XOR.
    const int cl0 = (lane & 3) | ((grp & 1) << 2);
    const int cl1 = cl0 ^ 4;
    const int kk  = grp & 7;           // == pl & 7 (wavebase, r4*16 are mult of 8)
    #pragma unroll
    for (int r4 = 0; r4 < 4; ++r4) {
        int pl = wavebase + r4 * 16 + grp;
        int c  = cellIdx[pl];
        const f32x4* src = (const f32x4*)(cells + (size_t)c * 32);
        f32x4 v0 = src[cl0];
        f32x4 v1 = src[cl1];
        f32x4* row = (f32x4*)(recs + pl * 32);
        row[cl0 ^ kk] = v0;
        row[cl1 ^ kk] = v1;
    }
    __syncthreads();

    int k = tid & 7;
    const f32x4* row = (const f32x4*)(recs + tid * 32);
    float v[24];
    #pragma unroll
    for (int c = 0; c < 6; ++c)
        *(f32x4*)(v + 4 * c) = row[c ^ k];

    float o0, o1, o2;
    tri_out(v, rd, gd, bd, o0, o1, o2);
    float* ob = out + (size_t)b * (3 * PLANE) + p;
    __builtin_nontemporal_store(o0, ob);
    __builtin_nontemporal_store(o1, ob + PLANE);
    __builtin_nontemporal_store(o2, ob + 2 * PLANE);
}

// ---------- Variant D: C + 16KB double-pumped exchange (2x occupancy) ----------
__global__ __launch_bounds__(256) void apply_coopD_kernel(
    const float* __restrict__ x, const float* __restrict__ cells,
    float* __restrict__ out) {
    __shared__ float recs[128 * 32];   // 16 KB
    __shared__ int cellIdx[256];

    const int tid = threadIdx.x;
    const int t = blockIdx.x * 256 + tid;
    const int b = t >> 20;
    const int p = t & (PLANE - 1);
    const float* xb = x + (size_t)b * (3 * PLANE) + p;
    float r  = __builtin_nontemporal_load(xb);
    float g  = __builtin_nontemporal_load(xb + PLANE);
    float bl = __builtin_nontemporal_load(xb + 2 * PLANE);
    int cell; float rd, gd, bd;
    decode_px(r, g, bl, cell, rd, gd, bd);
    cellIdx[tid] = cell;
    __syncthreads();

    const int lane = tid & 63;
    const int wave32 = (tid & 192) >> 1;   // wave * 32
    const int grp = lane >> 2;
    const int cl0 = (lane & 3) | ((grp & 1) << 2);
    const int cl1 = cl0 ^ 4;
    const int kk  = grp & 7;

    float* ob = out + (size_t)b * (3 * PLANE) + p;

    #pragma unroll
    for (int ph = 0; ph < 2; ++ph) {
        // all 4 waves gather this phase's 128 rows
        #pragma unroll
        for (int r2 = 0; r2 < 2; ++r2) {
            int row_id = wave32 + r2 * 16 + grp;          // 0..127
            int c = cellIdx[ph * 128 + row_id];
            const f32x4* src = (const f32x4*)(cells + (size_t)c * 32);
            f32x4 v0 = src[cl0];
            f32x4 v1 = src[cl1];
            f32x4* row = (f32x4*)(recs + row_id * 32);
            row[cl0 ^ kk] = v0;
            row[cl1 ^ kk] = v1;
        }
        __syncthreads();
        if ((tid >> 7) == ph) {                            // wave-uniform
            int rr = tid & 127;
            int k = rr & 7;
            const f32x4* row = (const f32x4*)(recs + rr * 32);
            float v[24];
            #pragma unroll
            for (int c = 0; c < 6; ++c)
                *(f32x4*)(v + 4 * c) = row[c ^ k];
            float o0, o1, o2;
            tri_out(v, rd, gd, bd, o0, o1, o2);
            __builtin_nontemporal_store(o0, ob);
            __builtin_nontemporal_store(o1, ob + PLANE);
            __builtin_nontemporal_store(o2, ob + 2 * PLANE);
        }
        if (ph == 0) __syncthreads();   // protect recs before phase-1 gather
    }
}

// ---------- fallback: direct gather from original layout ----------
__global__ __launch_bounds__(256) void apply_direct_kernel(
    const float* __restrict__ x, const float* __restrict__ lut,
    float* __restrict__ out) {
    int t = blockIdx.x * 256 + threadIdx.x;
    int b = t >> 20;
    int p = t & (PLANE - 1);
    const float* xb = x + (size_t)b * (3 * PLANE) + p;
    int cell; float rd, gd, bd;
    decode_px(xb[0], xb[PLANE], xb[2 * PLANE], cell, rd, gd, bd);
    int ri = cell & 31, gi = (cell >> 5) & 31, bi = cell >> 10;
    int id000 = ri + gi * DIM + bi * D2;

    float omr = 1.0f - rd, omg = 1.0f - gd, omb = 1.0f - bd;
    float w000 = omr*omg*omb, w100 = rd*omg*omb, w010 = omr*gd*omb, w110 = rd*gd*omb;
    float w001 = omr*omg*bd,  w101 = rd*omg*bd,  w011 = omr*gd*bd,  w111 = rd*gd*bd;

    float* ob = out + (size_t)b * (3 * PLANE) + p;
    #pragma unroll
    for (int ch = 0; ch < 3; ++ch) {
        const float* L = lut + ch * SHIFT + id000;
        float acc = w000 * L[0]        + w100 * L[1]
                  + w010 * L[DIM]      + w110 * L[DIM + 1]
                  + w001 * L[D2]       + w101 * L[D2 + 1]
                  + w011 * L[D2 + DIM] + w111 * L[D2 + DIM + 1];
        ob[(size_t)ch * PLANE] = acc;
    }
}

extern "C" void kernel_launch(void* const* d_in, const int* in_sizes, int n_in,
                              void* d_out, int out_size, void* d_ws, size_t ws_size,
                              hipStream_t stream) {
    const float* lut = (const float*)d_in[1];
    const float* x   = (const float*)d_in[2];
    float* out = (float*)d_out;

    (void)hipMemcpyAsync(out, lut, (size_t)LUT_ELEMS * sizeof(float),
                         hipMemcpyDeviceToDevice, stream);

    float* outimg = out + LUT_ELEMS;
    const size_t bytes128 = (size_t)NCELL * 32 * sizeof(float);  // 4 MiB

    if (ws_size >= bytes128) {
        float* cells = (float*)d_ws;
        build_cells128_kernel<<<NCELL * 32 / 256, 256, 0, stream>>>(lut, cells);

        const int half_pix = NPIX / 2;                  // images 0-3 vs 4-7
        apply_coopC_kernel<<<half_pix / 256, 256, 0, stream>>>(x, cells, outimg);
        const size_t off = (size_t)4 * (3 * PLANE);
        apply_coopD_kernel<<<half_pix / 256, 256, 0, stream>>>(
            x + off, cells, outimg + off);
    } else {
        apply_direct_kernel<<<NPIX / 256, 256, 0, stream>>>(x, lut, outimg);
    }
}

// Round 14
// 234.306 us; speedup vs baseline: 1.1836x; 1.0326x over previous
//
#include <hip/hip_runtime.h>

// TrilinearInterpolation: 33^3 x 3ch LUT applied to 8x3x1024x1024 image.
// d_out = [lut copy (107811)] ++ [output (25165824)].
//
// R10 lesson: half-image A/B dispatches (<60us) fall below the harness's
// 0xAA-poison fill dispatches (~60us) in rocprof top-5 -> unobservable.
// This round: variant D (phase-balanced swizzle + 16KB double-pumped
// exchange) on ALL images in one dispatch for full counter visibility.

typedef float f32x4 __attribute__((ext_vector_type(4)));

#define DIM    33
#define D2     (DIM * DIM)
#define SHIFT  (DIM * DIM * DIM)
#define LUT_ELEMS (3 * SHIFT)
#define NCELL  32768
#define PLANE  1048576
#define NPIX   (8 * PLANE)

// ---------- build 128B-padded records: cell -> 8 corners x 3ch (+8 pad) ----------
__global__ __launch_bounds__(256) void build_cells128_kernel(
    const float* __restrict__ lut, float* __restrict__ cells) {
    int t = blockIdx.x * 256 + threadIdx.x;     // NCELL*32 threads
    int cell = t >> 5;
    int j = t & 31;
    float v = 0.0f;
    if (j < 24) {
        int corner = j / 3;
        int ch = j - corner * 3;
        int ri = cell & 31, gi = (cell >> 5) & 31, bi = cell >> 10;
        int dr = corner & 1, dg = (corner >> 1) & 1, db = corner >> 2;
        v = lut[ch * SHIFT + (bi + db) * D2 + (gi + dg) * DIM + (ri + dr)];
    }
    cells[t] = v;
}

// ---------- shared helpers ----------
__device__ __forceinline__ void decode_px(float r, float g, float bl,
                                          int& cell, float& rd, float& gd, float& bd) {
    const float BIN = (float)(1.000001 / 32.0);
    float rs = r / BIN, gs = g / BIN, bs = bl / BIN;
    float rf = floorf(rs), gf = floorf(gs), bf = floorf(bs);
    rd = rs - rf; gd = gs - gf; bd = bs - bf;
    cell = (((int)bf) << 10) | (((int)gf) << 5) | ((int)rf);
}

__device__ __forceinline__ void tri_out(const float* v, float rd, float gd, float bd,
                                        float& o0, float& o1, float& o2) {
    float omr = 1.0f - rd, omg = 1.0f - gd, omb = 1.0f - bd;
    float w000 = omr*omg*omb, w100 = rd*omg*omb, w010 = omr*gd*omb, w110 = rd*gd*omb;
    float w001 = omr*omg*bd,  w101 = rd*omg*bd,  w011 = omr*gd*bd,  w111 = rd*gd*bd;
    o0 = w000*v[0] + w100*v[3] + w010*v[6]  + w110*v[9]  + w001*v[12] + w101*v[15] + w011*v[18] + w111*v[21];
    o1 = w000*v[1] + w100*v[4] + w010*v[7]  + w110*v[10] + w001*v[13] + w101*v[16] + w011*v[19] + w111*v[22];
    o2 = w000*v[2] + w100*v[5] + w010*v[8]  + w110*v[11] + w001*v[14] + w101*v[17] + w011*v[20] + w111*v[23];
}

// ---------- Variant D: phase-balanced swizzle + 16KB double-pumped exchange ----------
__global__ __launch_bounds__(256) void apply_coopD_kernel(
    const float* __restrict__ x, const float* __restrict__ cells,
    float* __restrict__ out) {
    __shared__ float recs[128 * 32];   // 16 KB
    __shared__ int cellIdx[256];

    const int tid = threadIdx.x;
    const int t = blockIdx.x * 256 + tid;
    const int b = t >> 20;
    const int p = t & (PLANE - 1);
    const float* xb = x + (size_t)b * (3 * PLANE) + p;
    float r  = __builtin_nontemporal_load(xb);
    float g  = __builtin_nontemporal_load(xb + PLANE);
    float bl = __builtin_nontemporal_load(xb + 2 * PLANE);
    int cell; float rd, gd, bd;
    decode_px(r, g, bl, cell, rd, gd, bd);
    cellIdx[tid] = cell;
    __syncthreads();

    const int lane = tid & 63;
    const int wave32 = (tid & 192) >> 1;   // wave * 32
    const int grp = lane >> 2;
    // 8-lane-phase bank balance: chunk ids cover 0..7 once per phase after XOR.
    const int cl0 = (lane & 3) | ((grp & 1) << 2);
    const int cl1 = cl0 ^ 4;
    const int kk  = grp & 7;

    float* ob = out + (size_t)b * (3 * PLANE) + p;

    #pragma unroll
    for (int ph = 0; ph < 2; ++ph) {
        // all 4 waves gather this phase's 128 rows
        #pragma unroll
        for (int r2 = 0; r2 < 2; ++r2) {
            int row_id = wave32 + r2 * 16 + grp;          // 0..127
            int c = cellIdx[ph * 128 + row_id];
            const f32x4* src = (const f32x4*)(cells + (size_t)c * 32);
            f32x4 v0 = src[cl0];
            f32x4 v1 = src[cl1];
            f32x4* row = (f32x4*)(recs + row_id * 32);
            row[cl0 ^ kk] = v0;
            row[cl1 ^ kk] = v1;
        }
        __syncthreads();
        if ((tid >> 7) == ph) {                            // wave-uniform
            int rr = tid & 127;
            int k = rr & 7;
            const f32x4* row = (const f32x4*)(recs + rr * 32);
            float v[24];
            #pragma unroll
            for (int c = 0; c < 6; ++c)
                *(f32x4*)(v + 4 * c) = row[c ^ k];
            float o0, o1, o2;
            tri_out(v, rd, gd, bd, o0, o1, o2);
            __builtin_nontemporal_store(o0, ob);
            __builtin_nontemporal_store(o1, ob + PLANE);
            __builtin_nontemporal_store(o2, ob + 2 * PLANE);
        }
        if (ph == 0) __syncthreads();   // protect recs before phase-1 gather
    }
}

// ---------- fallback: direct gather from original layout ----------
__global__ __launch_bounds__(256) void apply_direct_kernel(
    const float* __restrict__ x, const float* __restrict__ lut,
    float* __restrict__ out) {
    int t = blockIdx.x * 256 + threadIdx.x;
    int b = t >> 20;
    int p = t & (PLANE - 1);
    const float* xb = x + (size_t)b * (3 * PLANE) + p;
    int cell; float rd, gd, bd;
    decode_px(xb[0], xb[PLANE], xb[2 * PLANE], cell, rd, gd, bd);
    int ri = cell & 31, gi = (cell >> 5) & 31, bi = cell >> 10;
    int id000 = ri + gi * DIM + bi * D2;

    float omr = 1.0f - rd, omg = 1.0f - gd, omb = 1.0f - bd;
    float w000 = omr*omg*omb, w100 = rd*omg*omb, w010 = omr*gd*omb, w110 = rd*gd*omb;
    float w001 = omr*omg*bd,  w101 = rd*omg*bd,  w011 = omr*gd*bd,  w111 = rd*gd*bd;

    float* ob = out + (size_t)b * (3 * PLANE) + p;
    #pragma unroll
    for (int ch = 0; ch < 3; ++ch) {
        const float* L = lut + ch * SHIFT + id000;
        float acc = w000 * L[0]        + w100 * L[1]
                  + w010 * L[DIM]      + w110 * L[DIM + 1]
                  + w001 * L[D2]       + w101 * L[D2 + 1]
                  + w011 * L[D2 + DIM] + w111 * L[D2 + DIM + 1];
        ob[(size_t)ch * PLANE] = acc;
    }
}

extern "C" void kernel_launch(void* const* d_in, const int* in_sizes, int n_in,
                              void* d_out, int out_size, void* d_ws, size_t ws_size,
                              hipStream_t stream) {
    const float* lut = (const float*)d_in[1];
    const float* x   = (const float*)d_in[2];
    float* out = (float*)d_out;

    (void)hipMemcpyAsync(out, lut, (size_t)LUT_ELEMS * sizeof(float),
                         hipMemcpyDeviceToDevice, stream);

    float* outimg = out + LUT_ELEMS;
    const size_t bytes128 = (size_t)NCELL * 32 * sizeof(float);  // 4 MiB

    if (ws_size >= bytes128) {
        float* cells = (float*)d_ws;
        build_cells128_kernel<<<NCELL * 32 / 256, 256, 0, stream>>>(lut, cells);
        apply_coopD_kernel<<<NPIX / 256, 256, 0, stream>>>(x, cells, outimg);
    } else {
        apply_direct_kernel<<<NPIX / 256, 256, 0, stream>>>(x, lut, outimg);
    }
}